// Round 14
// baseline (130.813 us; speedup 1.0000x reference)
//
#include <hip/hip_runtime.h>

#define NF 160
#define NP 80
#define ND 64
#define NC 512
#define NV 81                  // stored v columns 0..80 (Hermitian half)
#define NPIXH (NF*NV)          // 12960
#define NPIXP 13056            // prm padding bound (never read >= NPIXH)
#define TWO_PI 6.283185307179586f

#define NBLK 512               // k_tail grid; launch_bounds(256,2) -> co-resident
#define BT 256
#define SPB 26                 // pixels per block (512*26 = 13312 >= 12960)
#define SPG 13                 // pixels per 128-thread group
#define NROWS 1024             // partial rows = 512 blocks * 2 groups
#define NGRP 64                // barrier groups
#define GSZ (NBLK/NGRP)        // 8
#define GRP_STRIDE 16          // 64B counter spacing

// prm slots (written phase A, read phase D)
#define IP_AR 0
#define IP_AI 1
#define IP_BR 2
#define IP_BI 3
#define IP_P  4
#define IP_Q  5
#define IP_R  6
#define IP_C2T 7
#define IP_S2T 8
#define IP_K  9
#define NPRM 10

__device__ __forceinline__ void rot(float& c, float& s, float stc, float sts) {
  float t1 = s * sts;
  float t2 = s * stc;
  float cn = fmaf(c, stc, -t1);
  s = fmaf(c, sts, t2);
  c = cn;
}

__device__ __forceinline__ void start_i_pow(int n, float& c, float& s) {
  switch (n & 3) {
    case 0: c = 1.f; s = 0.f; break;
    case 1: c = 0.f; s = 1.f; break;
    case 2: c = -1.f; s = 0.f; break;
    default: c = 0.f; s = -1.f; break;
  }
}

// ---- relaxed agent-scope atomic payload helpers (R7-proven) ----
__device__ __forceinline__ float at_load_f(const float* p) {
  unsigned u = __hip_atomic_load((const unsigned*)p, __ATOMIC_RELAXED, __HIP_MEMORY_SCOPE_AGENT);
  return __uint_as_float(u);
}
__device__ __forceinline__ void at_store_f(float* p, float v) {
  __hip_atomic_store((unsigned*)p, __float_as_uint(v), __ATOMIC_RELAXED, __HIP_MEMORY_SCOPE_AGENT);
}
__device__ __forceinline__ float2 at_load_f2(const float2* p) {
  unsigned long long u = __hip_atomic_load((const unsigned long long*)p, __ATOMIC_RELAXED, __HIP_MEMORY_SCOPE_AGENT);
  float2 v;
  v.x = __uint_as_float((unsigned)u);
  v.y = __uint_as_float((unsigned)(u >> 32));
  return v;
}
__device__ __forceinline__ void at_store_f2(float2* p, float2 v) {
  unsigned long long u = ((unsigned long long)__float_as_uint(v.y) << 32) | __float_as_uint(v.x);
  __hip_atomic_store((unsigned long long*)p, u, __ATOMIC_RELAXED, __HIP_MEMORY_SCOPE_AGENT);
}

// Fence-free grid barrier (R7-proven): monotonic two-level counters.
__device__ __forceinline__ void gbar(int* bar) {
  __syncthreads();
  if (threadIdx.x == 0) {
    int* gc = bar + (blockIdx.x & (NGRP - 1)) * GRP_STRIDE;
    int* root = bar + NGRP * GRP_STRIDE;
    int* gen = root + 16;
    asm volatile("s_waitcnt vmcnt(0)" ::: "memory");
    int g0 = __hip_atomic_load(gen, __ATOMIC_RELAXED, __HIP_MEMORY_SCOPE_AGENT);
    int a = __hip_atomic_fetch_add(gc, 1, __ATOMIC_RELAXED, __HIP_MEMORY_SCOPE_AGENT);
    if ((a & (GSZ - 1)) == (GSZ - 1)) {
      int r = __hip_atomic_fetch_add(root, 1, __ATOMIC_RELAXED, __HIP_MEMORY_SCOPE_AGENT);
      if ((r & (NGRP - 1)) == (NGRP - 1))
        __hip_atomic_fetch_add(gen, 1, __ATOMIC_RELAXED, __HIP_MEMORY_SCOPE_AGENT);
    }
    while (__hip_atomic_load(gen, __ATOMIC_RELAXED, __HIP_MEMORY_SCOPE_AGENT) == g0)
      __builtin_amdgcn_s_sleep(4);
    asm volatile("" ::: "memory");
  }
  __syncthreads();
}

// K1: T[d][a][v] = sum_b yw[d,a,b] * e^{-2pi i v (b-40)/160}, v in 0..80
__global__ __launch_bounds__(256) void k_fft_x(const float* __restrict__ patch,
                                               const float* __restrict__ gw,
                                               float2* __restrict__ T) {
  int idx = blockIdx.x * 256 + threadIdx.x;   // ND*NP*NV = 414720
  int v = idx % NV;
  int a = (idx / NV) % NP;
  int d = idx / (NV * NP);
  float c, s;
  start_i_pow(v, c, s);
  float stc, sts;
  sincosf(-TWO_PI * (float)v / (float)NF, &sts, &stc);
  const float* prow = patch + (size_t)(d * NP + a) * NP;
  const float* grow = gw + a * NP;
  float accR = 0.f, accI = 0.f;
#pragma unroll 4
  for (int b = 0; b < NP; ++b) {
    float f = prow[b] * grow[b];
    accR = fmaf(f, c, accR);
    accI = fmaf(f, s, accI);
    rot(c, s, stc, sts);
  }
  T[idx] = make_float2(accR, accI);
}

// K2: Y[d][u][v] = sum_a T[d][a][v] * e^{-2pi i u (a-40)/160}
__global__ __launch_bounds__(256) void k_fft_y(const float2* __restrict__ T,
                                               float2* __restrict__ Y) {
  int idx = blockIdx.x * 256 + threadIdx.x;   // 64*40*81 = 207360
  int v = idx % NV;
  int ug = (idx / NV) % 40;
  int d = idx / (NV * 40);
  float c[4], s[4], aR[4], aI[4], stc[4], sts[4];
#pragma unroll
  for (int j = 0; j < 4; ++j) {
    int u = ug * 4 + j;
    start_i_pow(u, c[j], s[j]);
    sincosf(-TWO_PI * (float)u / (float)NF, &sts[j], &stc[j]);
    aR[j] = 0.f; aI[j] = 0.f;
  }
  const float2* Tb = T + (size_t)(d * NP) * NV + v;
#pragma unroll 4
  for (int a = 0; a < NP; ++a) {
    float2 t = Tb[(size_t)a * NV];
#pragma unroll
    for (int j = 0; j < 4; ++j) {
      aR[j] = fmaf(t.x, c[j], aR[j]);
      aR[j] = fmaf(-t.y, s[j], aR[j]);
      aI[j] = fmaf(t.x, s[j], aI[j]);
      aI[j] = fmaf(t.y, c[j], aI[j]);
      rot(c[j], s[j], stc[j], sts[j]);
    }
  }
#pragma unroll
  for (int j = 0; j < 4; ++j) {
    int u = ug * 4 + j;
    Y[((size_t)d * NF + u) * NV + v] = make_float2(aR[j], aI[j]);
  }
}

// K3: fused tail. A: per-stripe prep (d-per-lane + shfl reduce) -> LDS.
// B: CPT=4 chains (two 128-thread groups). C: sum. D: argmin+ifftu. E: iffty.
__global__ __launch_bounds__(256, 2) void k_tail(
    const float2* __restrict__ Y, const float* __restrict__ delays,
    const float* __restrict__ kloss, const float* __restrict__ theta,
    const float* __restrict__ cand, float* __restrict__ out,
    float* __restrict__ prm, float* __restrict__ partial,
    float* __restrict__ loss, float2* __restrict__ G,
    int* __restrict__ bar) {
  __shared__ __align__(16) float yk_lds[SPB * 64];     // 6656 B
  __shared__ __align__(16) float prm_lds[SPB][20];     // 2080 B
  __shared__ float red[256];
  __shared__ float sl[256];
  __shared__ int si[256];
  __shared__ float xr[NF], xi[NF];

  // ---- phase A: prep for this block's 26 pixels ----
  {
    int wid = threadIdx.x >> 6;     // 0..3 (pixel-wave within round)
    int lane = threadIdx.x & 63;    // = d
    float dly = delays[lane];
    float d0 = delays[0], d1 = delays[1];
    for (int r = 0; r < 7; ++r) {
      int pl = r * 4 + wid;
      if (pl < SPB) {
        int pg = blockIdx.x * SPB + pl;
        bool valid = pg < NPIXH;
        float k = 0.f, c2t = 0.f, s2t = 0.f, wgt = 0.f;
        float cd = 1.f, sd = 0.f, y_x = 0.f, y_y = 0.f;
        int u = 0, v = 0;
        if (valid) {
          u = pg / NV; v = pg - u * NV;
          k = kloss[u * NF + v];
          float th = theta[((u + 80) % NF) * NF + ((v + 80) % NF)];
          c2t = cosf(2.f * th); s2t = sinf(2.f * th);
          if (v == 0 || v == 80) {
            if (u == 0 || u == 80) wgt = 1.f;
            else if (u < 80) wgt = 2.f;
            else wgt = 0.f;
          } else wgt = 2.f;
          sincosf(k * dly, &sd, &cd);
          float2 y = Y[((size_t)lane * NF + u) * NV + v];
          y_x = y.x; y_y = y.y;
        }
        float yk = sqrtf(fmaf(y_x, y_x, y_y * y_y)) * k;
        // per-lane moment terms
        float mAr = y_x * cd, mAi = y_y * cd, mBr = y_x * sd, mBi = y_y * sd;
        float mP = cd * cd, mQ = cd * sd, mR = sd * sd, mS = yk * yk;
#pragma unroll
        for (int off = 32; off > 0; off >>= 1) {
          mAr += __shfl_xor(mAr, off);
          mAi += __shfl_xor(mAi, off);
          mBr += __shfl_xor(mBr, off);
          mBi += __shfl_xor(mBi, off);
          mP += __shfl_xor(mP, off);
          mQ += __shfl_xor(mQ, off);
          mR += __shfl_xor(mR, off);
          mS += __shfl_xor(mS, off);
        }
        // yk -> quad layout (2jj, 63-2jj, 2jj+1, 62-2jj)
        int jj, el;
        if (lane < 32) { jj = lane >> 1; el = (lane & 1) ? 2 : 0; }
        else if (lane & 1) { jj = (63 - lane) >> 1; el = 1; }
        else { jj = (62 - lane) >> 1; el = 3; }
        yk_lds[pl * 64 + jj * 4 + el] = valid ? yk : 0.f;
        float cd0v = __shfl(cd, 0), sd0v = __shfl(sd, 0);
        float cd1v = __shfl(cd, 1), sd1v = __shfl(sd, 1);
        if (lane == 0) {
          float* pp = &prm_lds[pl][0];
          if (valid) {
            float tcd = 2.f * cosf(k * (d1 - d0));
            pp[0] = mAr; pp[1] = mAi; pp[2] = mBr; pp[3] = mBi;
            pp[4] = mP;  pp[5] = mQ;  pp[6] = mR;  pp[7] = mS;
            pp[8] = c2t; pp[9] = s2t; pp[10] = k;  pp[11] = wgt;
            pp[12] = cd0v; pp[13] = sd0v; pp[14] = cd1v; pp[15] = sd1v;
            pp[16] = tcd;
            at_store_f(&prm[IP_AR * NPIXP + pg], mAr);
            at_store_f(&prm[IP_AI * NPIXP + pg], mAi);
            at_store_f(&prm[IP_BR * NPIXP + pg], mBr);
            at_store_f(&prm[IP_BI * NPIXP + pg], mBi);
            at_store_f(&prm[IP_P * NPIXP + pg], mP);
            at_store_f(&prm[IP_Q * NPIXP + pg], mQ);
            at_store_f(&prm[IP_R * NPIXP + pg], mR);
            at_store_f(&prm[IP_C2T * NPIXP + pg], c2t);
            at_store_f(&prm[IP_S2T * NPIXP + pg], s2t);
            at_store_f(&prm[IP_K * NPIXP + pg], k);
          } else {
            pp[0] = 0.f; pp[1] = 0.f; pp[2] = 0.f; pp[3] = 0.f;
            pp[4] = 1.f; pp[5] = 0.f; pp[6] = 1.f; pp[7] = 0.f;
            pp[8] = 0.f; pp[9] = 0.f; pp[10] = 0.f; pp[11] = 0.f;
            pp[12] = 1.f; pp[13] = 0.f; pp[14] = 1.f; pp[15] = 0.f;
            pp[16] = 2.f;
          }
        }
      }
    }
  }
  __syncthreads();

  // ---- phase B: chains, CPT=4, two 128-thread groups ----
  {
    int g = threadIdx.x >> 7;       // 0,1
    int tp = threadIdx.x & 127;
    float dc[4], xx[4], yy[4], acc[4];
#pragma unroll
    for (int ci = 0; ci < 4; ++ci) {
      int c = tp + ci * 128;
      dc[ci] = cand[c * 3 + 0];
      xx[ci] = cand[c * 3 + 1];
      yy[ci] = cand[c * 3 + 2];
      acc[ci] = 0.f;
    }
    for (int i = 0; i < SPG; ++i) {
      int pl = g * SPG + i;
      const float* pp = &prm_lds[pl][0];
      float4 pA = *(const float4*)(pp);
      float4 pB = *(const float4*)(pp + 4);
      float4 pC = *(const float4*)(pp + 8);
      float4 pD = *(const float4*)(pp + 12);
      float tcd = pp[16];
      const float4* ykq = (const float4*)&yk_lds[pl * 64];
      float4 y0 = ykq[0];
      float A0[4], A1[4], B0[4], B1[4], M[4], F0[4], F1[4];
#pragma unroll
      for (int ci = 0; ci < 4; ++ci) {
        float w_ = fmaf(xx[ci], pC.x, fmaf(yy[ci], pC.y, dc[ci]));
        float sw, cw;
        __sincosf(pC.z * w_, &sw, &cw);
        float rr = fmaf(cw, pA.x, sw * pA.z);
        float ri = fmaf(cw, pA.y, sw * pA.w);
        float lhs = fmaf(cw * cw, pB.x, fmaf(2.f * cw * sw, pB.y, sw * sw * pB.z));
        float rabs = __builtin_amdgcn_sqrtf(fmaf(rr, rr, ri * ri));
        float rl = __builtin_amdgcn_rcpf(lhs);
        float e = fmaf(-lhs, rl, 1.f);
        rl = fmaf(rl, e, rl);
        float kX = pC.z * rabs * rl;
        F0[ci] = fmaf(kX * kX, lhs, pB.w);
        F1[ci] = -2.f * kX;
        float t0 = pD.x * cw, u0 = pD.y * sw;
        float t1 = pD.z * cw, u1 = pD.w * sw;
        A0[ci] = t0 + u0;  B0[ci] = t0 - u0;
        A1[ci] = t1 + u1;  B1[ci] = t1 - u1;
        float m = y0.x * fabsf(A0[ci]);
        m = fmaf(y0.y, fabsf(B0[ci]), m);
        m = fmaf(y0.z, fabsf(A1[ci]), m);
        m = fmaf(y0.w, fabsf(B1[ci]), m);
        M[ci] = m;
      }
#pragma unroll
      for (int jj = 1; jj < 16; ++jj) {
        float4 yk = ykq[jj];
#pragma unroll
        for (int ci = 0; ci < 4; ++ci) {
          float An = fmaf(tcd, A1[ci], -A0[ci]);
          float Bn = fmaf(tcd, B1[ci], -B0[ci]);
          float m = fmaf(yk.x, fabsf(An), M[ci]);
          m = fmaf(yk.y, fabsf(Bn), m);
          float An2 = fmaf(tcd, An, -A1[ci]);
          float Bn2 = fmaf(tcd, Bn, -B1[ci]);
          m = fmaf(yk.z, fabsf(An2), m);
          m = fmaf(yk.w, fabsf(Bn2), m);
          M[ci] = m;
          A0[ci] = An; A1[ci] = An2;
          B0[ci] = Bn; B1[ci] = Bn2;
        }
      }
#pragma unroll
      for (int ci = 0; ci < 4; ++ci)
        acc[ci] = fmaf(fmaf(F1[ci], M[ci], F0[ci]), pC.w, acc[ci]);
    }
    int row = blockIdx.x * 2 + g;
#pragma unroll
    for (int ci = 0; ci < 4; ++ci)
      at_store_f(&partial[(size_t)row * NC + tp + ci * 128], acc[ci]);
  }
  gbar(bar);

  // ---- phase C: loss[c] = sum over 1024 rows (every block does one c) ----
  {
    int c = blockIdx.x;
    float s = 0.f;
    for (int j = threadIdx.x; j < NROWS; j += 256)
      s += at_load_f(&partial[(size_t)j * NC + c]);
    red[threadIdx.x] = s;
    __syncthreads();
    for (int off = 128; off > 0; off >>= 1) {
      if (threadIdx.x < off) red[threadIdx.x] += red[threadIdx.x + off];
      __syncthreads();
    }
    if (threadIdx.x == 0) at_store_f(&loss[c], red[0]);
  }
  gbar(bar);

  // ---- phase D: redundant argmin + ifftu (blocks 0..159) ----
  if (blockIdx.x < NF) {
    int c1 = threadIdx.x, c2 = threadIdx.x + 256;
    float s1 = at_load_f(&loss[c1]), s2 = at_load_f(&loss[c2]);
    float l; int i;
    if (s2 < s1) { l = s2; i = c2; } else { l = s1; i = c1; }
    sl[threadIdx.x] = l; si[threadIdx.x] = i;
    __syncthreads();
    for (int off = 128; off > 0; off >>= 1) {
      if (threadIdx.x < off) {
        float l2 = sl[threadIdx.x + off]; int i2 = si[threadIdx.x + off];
        if (l2 < sl[threadIdx.x] || (l2 == sl[threadIdx.x] && i2 < si[threadIdx.x])) {
          sl[threadIdx.x] = l2; si[threadIdx.x] = i2;
        }
      }
      __syncthreads();
    }
    int bi = si[0];
    if (blockIdx.x == 0 && threadIdx.x == 0) {
      out[6400] = cand[bi * 3 + 0];
      out[6401] = cand[bi * 3 + 1];
      out[6402] = cand[bi * 3 + 2];
      out[6403] = sl[0] * (1.f / 1638400.f);
    }
    int u = blockIdx.x;
    float dc = cand[bi * 3 + 0], xx = cand[bi * 3 + 1], yy = cand[bi * 3 + 2];
    int v = threadIdx.x;
    if (v < NF) {
      float sign = 1.f;
      int ph;
      if (v <= 80) {
        ph = u * NV + v;
      } else {
        int u2 = (NF - u) % NF;
        ph = u2 * NV + (NF - v);
        sign = -1.f;
      }
      float Ar = at_load_f(&prm[IP_AR * NPIXP + ph]);
      float Ai = at_load_f(&prm[IP_AI * NPIXP + ph]);
      float Br = at_load_f(&prm[IP_BR * NPIXP + ph]);
      float Bi = at_load_f(&prm[IP_BI * NPIXP + ph]);
      float Pm = at_load_f(&prm[IP_P * NPIXP + ph]);
      float Qm = at_load_f(&prm[IP_Q * NPIXP + ph]);
      float Rm = at_load_f(&prm[IP_R * NPIXP + ph]);
      float c2t = at_load_f(&prm[IP_C2T * NPIXP + ph]);
      float s2t = at_load_f(&prm[IP_S2T * NPIXP + ph]);
      float k = at_load_f(&prm[IP_K * NPIXP + ph]);
      float w_ = fmaf(xx, c2t, fmaf(yy, s2t, dc));
      float sw, cw;
      sincosf(k * w_, &sw, &cw);
      float rr = fmaf(cw, Ar, sw * Br);
      float ri = fmaf(cw, Ai, sw * Bi);
      float lhs = fmaf(cw * cw, Pm, fmaf(2.f * cw * sw, Qm, sw * sw * Rm));
      xr[v] = rr / lhs;
      xi[v] = sign * ri / lhs;
    }
    __syncthreads();
    int b = threadIdx.x;
    if (b < NP) {
      int xb = (b + 120) % NF;
      float stc, sts;
      sincosf(TWO_PI * (float)xb / (float)NF, &sts, &stc);
      float c = 1.f, s = 0.f, accR = 0.f, accI = 0.f;
#pragma unroll 4
      for (int vv = 0; vv < NF; ++vv) {
        float xrv = xr[vv], xiv = xi[vv];
        accR = fmaf(xrv, c, accR); accR = fmaf(-xiv, s, accR);
        accI = fmaf(xrv, s, accI); accI = fmaf(xiv, c, accI);
        rot(c, s, stc, sts);
      }
      at_store_f2(&G[(size_t)u * NP + b], make_float2(accR, accI));
    }
  }
  gbar(bar);

  // ---- phase E: iffty (blocks 0..24, 256 items each) ----
  if (blockIdx.x < 25) {
    int idx = blockIdx.x * 256 + threadIdx.x;   // 0..6399
    int b = idx % NP;
    int a = idx / NP;
    int ya = (a + 120) % NF;
    float stc, sts;
    sincosf(TWO_PI * (float)ya / (float)NF, &sts, &stc);
    float c = 1.f, s = 0.f, accR = 0.f;
#pragma unroll 4
    for (int u = 0; u < NF; ++u) {
      float2 g2 = at_load_f2(&G[(size_t)u * NP + b]);
      accR = fmaf(g2.x, c, accR);
      accR = fmaf(-g2.y, s, accR);
      rot(c, s, stc, sts);
    }
    out[idx] = accR * (1.f / 25600.f);
  }
}

extern "C" void kernel_launch(void* const* d_in, const int* in_sizes, int n_in,
                              void* d_out, int out_size, void* d_ws, size_t ws_size,
                              hipStream_t stream) {
  (void)in_sizes; (void)n_in; (void)out_size; (void)ws_size;
  const float* patch  = (const float*)d_in[0];
  const float* gw     = (const float*)d_in[1];
  const float* delays = (const float*)d_in[2];
  const float* theta  = (const float*)d_in[4];
  const float* kloss  = (const float*)d_in[5];
  const float* cand   = (const float*)d_in[6];
  float* out = (float*)d_out;

  char* ws = (char*)d_ws;
  size_t off = 0;
  float2* Y = (float2*)(ws + off);      off += (size_t)ND * NF * NV * 8;     // 6,635,520
  float2* T = (float2*)(ws + off);      off += (size_t)ND * NP * NV * 8;     // 3,317,760
  float* prm = (float*)(ws + off);      off += (size_t)NPRM * NPIXP * 4;     //   522,240
  float* partial = (float*)(ws + off);  off += (size_t)NROWS * NC * 4;       // 2,097,152
  float* loss = (float*)(ws + off);     off += (size_t)NC * 4;               //     2,048
  float2* G = (float2*)(ws + off);      off += (size_t)NF * NP * 8;          //   102,400
  off = (off + 255) & ~(size_t)255;
  int* bar = (int*)(ws + off);          // 64 spaced group counters + root + gen

  hipMemsetAsync(bar, 0, 8192, stream);
  hipLaunchKernelGGL(k_fft_x, dim3((ND * NP * NV) / 256), dim3(256), 0, stream,
                     patch, gw, T);
  hipLaunchKernelGGL(k_fft_y, dim3((ND * 40 * NV) / 256), dim3(256), 0, stream,
                     T, Y);
  hipLaunchKernelGGL(k_tail, dim3(NBLK), dim3(BT), 0, stream,
                     Y, delays, kloss, theta, cand, out, prm, partial, loss, G, bar);
}

// Round 15
// 94.723 us; speedup vs baseline: 1.3810x; 1.3810x over previous
//
#include <hip/hip_runtime.h>

#define NF 160
#define NP 80
#define ND 64
#define NC 512
#define NV 81                  // stored v columns 0..80 (Hermitian half)
#define NPIXH (NF*NV)          // 12960
#define NPIXP 13056            // padded: 408*32 = 1632*8
#define NSTR 1632              // pixel stripes (grid.x of k_cand)
#define STRIPE 8               // pixels per stripe
#define RECQ 21                // float4 planes per pixel record
#define BT 128                 // k_cand block threads
#define CPT 4                  // candidates per thread (128*4 = 512 = NC)
#define TWO_PI 6.283185307179586f

// per-pixel precomputed parameter slots (for k_amin_ifftu)
#define IP_AR 0
#define IP_AI 1
#define IP_BR 2
#define IP_BI 3
#define IP_P  4
#define IP_Q  5
#define IP_R  6
#define IP_C2T 7
#define IP_S2T 8
#define IP_K  9
#define NPRM 10

__device__ __forceinline__ void rot(float& c, float& s, float stc, float sts) {
  float t1 = s * sts;
  float t2 = s * stc;
  float cn = fmaf(c, stc, -t1);
  s = fmaf(c, sts, t2);
  c = cn;
}

__device__ __forceinline__ void start_i_pow(int n, float& c, float& s) {
  switch (n & 3) {
    case 0: c = 1.f; s = 0.f; break;
    case 1: c = 0.f; s = 1.f; break;
    case 2: c = -1.f; s = 0.f; break;
    default: c = 0.f; s = -1.f; break;
  }
}

// K1: T[d][a][v] = sum_b yw[d,a,b] * e^{-2pi i v (b-40)/160}, v in 0..80
__global__ __launch_bounds__(256) void k_fft_x(const float* __restrict__ patch,
                                               const float* __restrict__ gw,
                                               float2* __restrict__ T) {
  int idx = blockIdx.x * 256 + threadIdx.x;   // ND*NP*NV = 414720
  int v = idx % NV;
  int a = (idx / NV) % NP;
  int d = idx / (NV * NP);
  float c, s;
  start_i_pow(v, c, s);
  float stc, sts;
  sincosf(-TWO_PI * (float)v / (float)NF, &sts, &stc);
  const float* prow = patch + (size_t)(d * NP + a) * NP;
  const float* grow = gw + a * NP;
  float accR = 0.f, accI = 0.f;
#pragma unroll 4
  for (int b = 0; b < NP; ++b) {
    float f = prow[b] * grow[b];
    accR = fmaf(f, c, accR);
    accI = fmaf(f, s, accI);
    rot(c, s, stc, sts);
  }
  T[idx] = make_float2(accR, accI);
}

// K2: Y[d][u][v] = sum_a T[d][a][v] * e^{-2pi i u (a-40)/160}
__global__ __launch_bounds__(256) void k_fft_y(const float2* __restrict__ T,
                                               float2* __restrict__ Y) {
  int idx = blockIdx.x * 256 + threadIdx.x;   // 64*40*81 = 207360
  int v = idx % NV;
  int ug = (idx / NV) % 40;
  int d = idx / (NV * 40);
  float c[4], s[4], aR[4], aI[4], stc[4], sts[4];
#pragma unroll
  for (int j = 0; j < 4; ++j) {
    int u = ug * 4 + j;
    start_i_pow(u, c[j], s[j]);
    sincosf(-TWO_PI * (float)u / (float)NF, &sts[j], &stc[j]);
    aR[j] = 0.f; aI[j] = 0.f;
  }
  const float2* Tb = T + (size_t)(d * NP) * NV + v;
#pragma unroll 4
  for (int a = 0; a < NP; ++a) {
    float2 t = Tb[(size_t)a * NV];
#pragma unroll
    for (int j = 0; j < 4; ++j) {
      aR[j] = fmaf(t.x, c[j], aR[j]);
      aR[j] = fmaf(-t.y, s[j], aR[j]);
      aI[j] = fmaf(t.x, s[j], aI[j]);
      aI[j] = fmaf(t.y, c[j], aI[j]);
      rot(c[j], s[j], stc[j], sts[j]);
    }
  }
#pragma unroll
  for (int j = 0; j < 4; ++j) {
    int u = ug * 4 + j;
    Y[((size_t)d * NF + u) * NV + v] = make_float2(aR[j], aI[j]);
  }
}

// K3 v2: d-sliced prep. Block = 8 d-groups x 32 pixels; grid = 408.
// Each thread: 8 sincos + 8 Y loads -> partial moments; LDS reduce over
// d-groups; quad-pack yk; write rec4 planes 0..20 + prm slots.
__global__ __launch_bounds__(256) void k_prep(const float2* __restrict__ Y,
                                              const float* __restrict__ delays,
                                              const float* __restrict__ kloss,
                                              const float* __restrict__ theta,
                                              float4* __restrict__ rec4,
                                              float* __restrict__ prm) {
  __shared__ float ykl[32][65];     // [pixel][d] (+pad)
  __shared__ float mom[8][32][9];   // [dgroup][pixel][val] (+pad)
  int t = threadIdx.x;
  int dg = t >> 5;                  // 0..7
  int pl = t & 31;                  // 0..31
  int p = blockIdx.x * 32 + pl;
  bool valid = p < NPIXH;
  float k = 0.f, c2t = 0.f, s2t = 0.f, wgt = 0.f;
  int u = 0, v = 0;
  if (valid) {
    u = p / NV; v = p - u * NV;
    k = kloss[u * NF + v];
    float th = theta[((u + 80) % NF) * NF + ((v + 80) % NF)];
    c2t = cosf(2.f * th); s2t = sinf(2.f * th);
    if (v == 0 || v == 80) {
      if (u == 0 || u == 80) wgt = 1.f;
      else if (u < 80) wgt = 2.f;
      else wgt = 0.f;
    } else wgt = 2.f;
  }
  float mAr = 0.f, mAi = 0.f, mBr = 0.f, mBi = 0.f;
  float mP = 0.f, mQ = 0.f, mR = 0.f, mS = 0.f;
#pragma unroll
  for (int j = 0; j < 8; ++j) {
    int d = dg * 8 + j;
    float sd, cd;
    sincosf(k * delays[d], &sd, &cd);
    float yx = 0.f, yy = 0.f;
    if (valid) {
      float2 y = Y[((size_t)d * NF + u) * NV + v];
      yx = y.x; yy = y.y;
    }
    mAr = fmaf(yx, cd, mAr);  mAi = fmaf(yy, cd, mAi);
    mBr = fmaf(yx, sd, mBr);  mBi = fmaf(yy, sd, mBi);
    mP = fmaf(cd, cd, mP);  mQ = fmaf(cd, sd, mQ);  mR = fmaf(sd, sd, mR);
    float yk = sqrtf(fmaf(yx, yx, yy * yy)) * k;
    ykl[pl][d] = yk;
    mS = fmaf(yk, yk, mS);
  }
  mom[dg][pl][0] = mAr; mom[dg][pl][1] = mAi;
  mom[dg][pl][2] = mBr; mom[dg][pl][3] = mBi;
  mom[dg][pl][4] = mP;  mom[dg][pl][5] = mQ;
  mom[dg][pl][6] = mR;  mom[dg][pl][7] = mS;
  __syncthreads();
  {
    int pl2 = t >> 3, val = t & 7;
    float s = 0.f;
#pragma unroll
    for (int g2 = 0; g2 < 8; ++g2) s += mom[g2][pl2][val];
    mom[0][pl2][val] = s;
  }
  __syncthreads();
  // quad writes: thread (pl3 = t>>3, q2 = t&7) writes quads 2*q2, 2*q2+1
  {
    int pl3 = t >> 3, q2 = t & 7;
    int p3 = blockIdx.x * 32 + pl3;
#pragma unroll
    for (int h = 0; h < 2; ++h) {
      int jj = q2 * 2 + h;
      float4 q = make_float4(ykl[pl3][2 * jj], ykl[pl3][63 - 2 * jj],
                             ykl[pl3][2 * jj + 1], ykl[pl3][62 - 2 * jj]);
      rec4[(size_t)jj * NPIXP + p3] = q;
    }
  }
  // param planes: threads 0..31 (dg==0) own their pixel's scalars
  if (dg == 0) {
    float Ar = mom[0][pl][0], Ai = mom[0][pl][1];
    float Br = mom[0][pl][2], Bi = mom[0][pl][3];
    float Pm = mom[0][pl][4], Qm = mom[0][pl][5];
    float Rm = mom[0][pl][6], S0 = mom[0][pl][7];
    if (valid) {
      float d0 = delays[0], d1 = delays[1];
      float sd0f, cd0f, sd1f, cd1f;
      sincosf(k * d0, &sd0f, &cd0f);
      sincosf(k * d1, &sd1f, &cd1f);
      float tcd = 2.f * cosf(k * (d1 - d0));
      rec4[(size_t)16 * NPIXP + p] = make_float4(Ar, Ai, Br, Bi);
      rec4[(size_t)17 * NPIXP + p] = make_float4(Pm, Qm, Rm, S0);
      rec4[(size_t)18 * NPIXP + p] = make_float4(c2t, s2t, k, wgt);
      rec4[(size_t)19 * NPIXP + p] = make_float4(cd0f, sd0f, cd1f, sd1f);
      rec4[(size_t)20 * NPIXP + p] = make_float4(tcd, 0.f, 0.f, 0.f);
      prm[IP_AR * NPIXP + p] = Ar;   prm[IP_AI * NPIXP + p] = Ai;
      prm[IP_BR * NPIXP + p] = Br;   prm[IP_BI * NPIXP + p] = Bi;
      prm[IP_P * NPIXP + p] = Pm;    prm[IP_Q * NPIXP + p] = Qm;
      prm[IP_R * NPIXP + p] = Rm;    prm[IP_C2T * NPIXP + p] = c2t;
      prm[IP_S2T * NPIXP + p] = s2t; prm[IP_K * NPIXP + p] = k;
    } else {
      rec4[(size_t)16 * NPIXP + p] = make_float4(0.f, 0.f, 0.f, 0.f);
      rec4[(size_t)17 * NPIXP + p] = make_float4(1.f, 0.f, 1.f, 0.f);
      rec4[(size_t)18 * NPIXP + p] = make_float4(0.f, 0.f, 0.f, 0.f);
      rec4[(size_t)19 * NPIXP + p] = make_float4(1.f, 0.f, 1.f, 0.f);
      rec4[(size_t)20 * NPIXP + p] = make_float4(2.f, 0.f, 0.f, 0.f);
    }
  }
}

// K4: CPT=4 candidates per thread, 128-thread block covers all 512
// candidates; one LDS record read feeds 4 chains; 1-ahead yk prefetch.
__global__ __launch_bounds__(BT) void k_cand(const float4* __restrict__ rec4,
                                             const float* __restrict__ cand,
                                             float* __restrict__ partial) {
  __shared__ float4 buf[STRIPE][RECQ];        // 2688 B
  int t = threadIdx.x;
  int p0 = blockIdx.x * STRIPE;               // 1632*8 = 13056 exactly
  float dc[CPT], xx[CPT], yy[CPT], acc[CPT];
#pragma unroll
  for (int ci = 0; ci < CPT; ++ci) {
    int c = t + ci * BT;
    dc[ci] = cand[c * 3 + 0];
    xx[ci] = cand[c * 3 + 1];
    yy[ci] = cand[c * 3 + 2];
    acc[ci] = 0.f;
  }
  for (int q = t; q < STRIPE * RECQ; q += BT) {   // 168 chunks, 2 rounds
    int px = q / RECQ, qq = q - px * RECQ;
    buf[px][qq] = rec4[(size_t)qq * NPIXP + (p0 + px)];
  }
  __syncthreads();
#pragma unroll
  for (int i = 0; i < STRIPE; ++i) {
    const float4* r = &buf[i][0];
    float4 pA = r[16];                        // Ar,Ai,Br,Bi
    float4 pB = r[17];                        // Pm,Qm,Rm,S0
    float4 pC = r[18];                        // c2t,s2t,k,wgt
    float4 pD = r[19];                        // cd0,sd0,cd1,sd1
    float tcd = r[20].x;
    float4 y0 = r[0];
    float A0[CPT], A1[CPT], B0[CPT], B1[CPT], M[CPT], F0[CPT], F1[CPT];
#pragma unroll
    for (int ci = 0; ci < CPT; ++ci) {
      float w_ = fmaf(xx[ci], pC.x, fmaf(yy[ci], pC.y, dc[ci]));
      float sw, cw;
      __sincosf(pC.z * w_, &sw, &cw);
      float rr = fmaf(cw, pA.x, sw * pA.z);
      float ri = fmaf(cw, pA.y, sw * pA.w);
      float lhs = fmaf(cw * cw, pB.x, fmaf(2.f * cw * sw, pB.y, sw * sw * pB.z));
      float rabs = __builtin_amdgcn_sqrtf(fmaf(rr, rr, ri * ri));
      float rl = __builtin_amdgcn_rcpf(lhs);
      float e = fmaf(-lhs, rl, 1.f);
      rl = fmaf(rl, e, rl);                   // refined 1/lhs
      float kX = pC.z * rabs * rl;
      F0[ci] = fmaf(kX * kX, lhs, pB.w);      // contrib = F0 + F1*M
      F1[ci] = -2.f * kX;
      float t0 = pD.x * cw, u0 = pD.y * sw;
      float t1 = pD.z * cw, u1 = pD.w * sw;
      A0[ci] = t0 + u0;  B0[ci] = t0 - u0;    // cos(k d0 -/+ kw)
      A1[ci] = t1 + u1;  B1[ci] = t1 - u1;    // cos(k d1 -/+ kw)
      float m = y0.x * fabsf(A0[ci]);
      m = fmaf(y0.y, fabsf(B0[ci]), m);
      m = fmaf(y0.z, fabsf(A1[ci]), m);
      m = fmaf(y0.w, fabsf(B1[ci]), m);
      M[ci] = m;
    }
    float4 ykn = r[1];
#pragma unroll
    for (int jj = 1; jj < 16; ++jj) {
      float4 yk = ykn;
      if (jj < 15) ykn = r[jj + 1];           // 1-ahead prefetch
#pragma unroll
      for (int ci = 0; ci < CPT; ++ci) {
        float An = fmaf(tcd, A1[ci], -A0[ci]);
        float Bn = fmaf(tcd, B1[ci], -B0[ci]);
        float m = fmaf(yk.x, fabsf(An), M[ci]);
        m = fmaf(yk.y, fabsf(Bn), m);
        float An2 = fmaf(tcd, An, -A1[ci]);
        float Bn2 = fmaf(tcd, Bn, -B1[ci]);
        m = fmaf(yk.z, fabsf(An2), m);
        m = fmaf(yk.w, fabsf(Bn2), m);
        M[ci] = m;
        A0[ci] = An; A1[ci] = An2;
        B0[ci] = Bn; B1[ci] = Bn2;
      }
    }
#pragma unroll
    for (int ci = 0; ci < CPT; ++ci)
      acc[ci] = fmaf(fmaf(F1[ci], M[ci], F0[ci]), pC.w, acc[ci]);
  }
#pragma unroll
  for (int ci = 0; ci < CPT; ++ci)
    partial[(size_t)blockIdx.x * NC + t + ci * BT] = acc[ci];
}

// K4b: loss[c] = sum over stripes — one block per candidate, parallel loads,
// deterministic LDS tree reduction.
__global__ __launch_bounds__(256) void k_sum(const float* __restrict__ partial,
                                             float* __restrict__ loss) {
  __shared__ float red[256];
  int c = blockIdx.x;                         // 512 blocks
  float s = 0.f;
  for (int j = threadIdx.x; j < NSTR; j += 256)
    s += partial[(size_t)j * NC + c];
  red[threadIdx.x] = s;
  __syncthreads();
  for (int off = 128; off > 0; off >>= 1) {
    if (threadIdx.x < off) red[threadIdx.x] += red[threadIdx.x + off];
    __syncthreads();
  }
  if (threadIdx.x == 0) loss[c] = red[0];
}

// K5: fused redundant argmin (per block) + ifft_u row DFT (blocks 0..159)
__global__ __launch_bounds__(256) void k_amin_ifftu(const float* __restrict__ loss,
                                                    const float* __restrict__ prm,
                                                    const float* __restrict__ cand,
                                                    float* __restrict__ out,
                                                    float2* __restrict__ G) {
  __shared__ float sl[256];
  __shared__ int si[256];
  __shared__ float xr[NF], xi[NF];
  int c1 = threadIdx.x, c2 = threadIdx.x + 256;
  float s1 = loss[c1], s2 = loss[c2];
  float l; int i;
  if (s2 < s1) { l = s2; i = c2; } else { l = s1; i = c1; }
  sl[threadIdx.x] = l; si[threadIdx.x] = i;
  __syncthreads();
  for (int off = 128; off > 0; off >>= 1) {
    if (threadIdx.x < off) {
      float l2 = sl[threadIdx.x + off]; int i2 = si[threadIdx.x + off];
      if (l2 < sl[threadIdx.x] || (l2 == sl[threadIdx.x] && i2 < si[threadIdx.x])) {
        sl[threadIdx.x] = l2; si[threadIdx.x] = i2;
      }
    }
    __syncthreads();
  }
  int bi = si[0];
  if (blockIdx.x == 0 && threadIdx.x == 0) {
    out[6400] = cand[bi * 3 + 0];
    out[6401] = cand[bi * 3 + 1];
    out[6402] = cand[bi * 3 + 2];
    out[6403] = sl[0] * (1.f / 1638400.f);
  }
  int u = blockIdx.x;
  float dc = cand[bi * 3 + 0], xx = cand[bi * 3 + 1], yy = cand[bi * 3 + 2];
  int v = threadIdx.x;
  if (v < NF) {
    float sign = 1.f;
    int ph;
    if (v <= 80) {
      ph = u * NV + v;
    } else {
      int u2 = (NF - u) % NF;
      ph = u2 * NV + (NF - v);
      sign = -1.f;
    }
    float Ar = prm[IP_AR * NPIXP + ph], Ai = prm[IP_AI * NPIXP + ph];
    float Br = prm[IP_BR * NPIXP + ph], Bi = prm[IP_BI * NPIXP + ph];
    float Pm = prm[IP_P * NPIXP + ph], Qm = prm[IP_Q * NPIXP + ph], Rm = prm[IP_R * NPIXP + ph];
    float c2t = prm[IP_C2T * NPIXP + ph], s2t = prm[IP_S2T * NPIXP + ph];
    float k = prm[IP_K * NPIXP + ph];
    float w_ = fmaf(xx, c2t, fmaf(yy, s2t, dc));
    float sw, cw;
    sincosf(k * w_, &sw, &cw);
    float rr = fmaf(cw, Ar, sw * Br);
    float ri = fmaf(cw, Ai, sw * Bi);
    float lhs = fmaf(cw * cw, Pm, fmaf(2.f * cw * sw, Qm, sw * sw * Rm));
    xr[v] = rr / lhs;
    xi[v] = sign * ri / lhs;
  }
  __syncthreads();
  int b = threadIdx.x;
  if (b < NP) {
    int xb = (b + 120) % NF;
    float stc, sts;
    sincosf(TWO_PI * (float)xb / (float)NF, &sts, &stc);
    float c = 1.f, s = 0.f, accR = 0.f, accI = 0.f;
#pragma unroll 4
    for (int vv = 0; vv < NF; ++vv) {
      float xrv = xr[vv], xiv = xi[vv];
      accR = fmaf(xrv, c, accR); accR = fmaf(-xiv, s, accR);
      accI = fmaf(xrv, s, accI); accI = fmaf(xiv, c, accI);
      rot(c, s, stc, sts);
    }
    G[(size_t)u * NP + b] = make_float2(accR, accI);
  }
}

// K6 v2: ifft_y u-sliced 4-way: block = 4 slices x 64 outputs, grid = 100.
// out[a][b] = Re(sum_u G[u][b] e^{+2pi i ya u/160})/25600
__global__ __launch_bounds__(256) void k_ifft_y(const float2* __restrict__ G,
                                                float* __restrict__ out) {
  __shared__ float red[4][65];
  int t = threadIdx.x;
  int o = t & 63;
  int slc = t >> 6;                           // 0..3, u in [40*slc, 40*slc+40)
  int idx = blockIdx.x * 64 + o;              // 6400 outputs
  int b = idx % NP;
  int a = idx / NP;
  int ya = (a + 120) % NF;
  float stc, sts;
  sincosf(TWO_PI * (float)ya / (float)NF, &sts, &stc);
  float c, s;
  start_i_pow(ya * slc, c, s);                // e^{2pi i ya (40 slc)/160} = i^(ya slc)
  float accR = 0.f;
  const float2* Gb = G + (size_t)(slc * 40) * NP + b;
#pragma unroll 4
  for (int j = 0; j < 40; ++j) {
    float2 g = Gb[(size_t)j * NP];
    accR = fmaf(g.x, c, accR);
    accR = fmaf(-g.y, s, accR);
    rot(c, s, stc, sts);
  }
  red[slc][o] = accR;
  __syncthreads();
  if (t < 64) {
    float s4 = ((red[0][t] + red[1][t]) + (red[2][t] + red[3][t]));
    out[blockIdx.x * 64 + t] = s4 * (1.f / 25600.f);
  }
}

extern "C" void kernel_launch(void* const* d_in, const int* in_sizes, int n_in,
                              void* d_out, int out_size, void* d_ws, size_t ws_size,
                              hipStream_t stream) {
  (void)in_sizes; (void)n_in; (void)out_size; (void)ws_size;
  const float* patch  = (const float*)d_in[0];
  const float* gw     = (const float*)d_in[1];
  const float* delays = (const float*)d_in[2];
  const float* theta  = (const float*)d_in[4];
  const float* kloss  = (const float*)d_in[5];
  const float* cand   = (const float*)d_in[6];
  float* out = (float*)d_out;

  char* ws = (char*)d_ws;
  size_t off = 0;
  float2* Y = (float2*)(ws + off);      off += (size_t)ND * NF * NV * 8;     // 6,635,520
  float2* T = (float2*)(ws + off);      off += (size_t)ND * NP * NV * 8;     // 3,317,760
  float4* rec4 = (float4*)(ws + off);   off += (size_t)RECQ * NPIXP * 16;    // 4,386,816
  float* prm = (float*)(ws + off);      off += (size_t)NPRM * NPIXP * 4;     //   522,240
  float* partial = (float*)(ws + off);  off += (size_t)NSTR * NC * 4;        // 3,342,336
  float* loss = (float*)(ws + off);     off += (size_t)NC * 4;               //     2,048
  float2* G = (float2*)(ws + off);      off += (size_t)NF * NP * 8;          //   102,400

  hipLaunchKernelGGL(k_fft_x, dim3((ND * NP * NV) / 256), dim3(256), 0, stream, patch, gw, T);
  hipLaunchKernelGGL(k_fft_y, dim3((ND * 40 * NV) / 256), dim3(256), 0, stream, T, Y);
  hipLaunchKernelGGL(k_prep, dim3(408), dim3(256), 0, stream, Y, delays, kloss, theta, rec4, prm);
  hipLaunchKernelGGL(k_cand, dim3(NSTR), dim3(BT), 0, stream, rec4, cand, partial);
  hipLaunchKernelGGL(k_sum, dim3(NC), dim3(256), 0, stream, partial, loss);
  hipLaunchKernelGGL(k_amin_ifftu, dim3(NF), dim3(256), 0, stream, loss, prm, cand, out, G);
  hipLaunchKernelGGL(k_ifft_y, dim3(100), dim3(256), 0, stream, G, out);
}

// Round 16
// 90.279 us; speedup vs baseline: 1.4490x; 1.0492x over previous
//
#include <hip/hip_runtime.h>

#define NF 160
#define NP 80
#define ND 64
#define NC 512
#define NV 81                  // stored v columns 0..80 (Hermitian half)
#define NPIXH (NF*NV)          // 12960
#define NPIXP 13056            // padded: 1632*8
#define NSTR 1632              // pixel stripes (grid.x of k_cand)
#define STRIPE 8               // pixels per stripe
#define RECQ 21                // float4 planes per pixel record (LDS-only now)
#define BT 128                 // k_cand block threads
#define CPT 4                  // candidates per thread (128*4 = 512 = NC)
#define TWO_PI 6.283185307179586f

// per-pixel precomputed parameter slots (for k_amin_ifftu)
#define IP_AR 0
#define IP_AI 1
#define IP_BR 2
#define IP_BI 3
#define IP_P  4
#define IP_Q  5
#define IP_R  6
#define IP_C2T 7
#define IP_S2T 8
#define IP_K  9
#define NPRM 10

__device__ __forceinline__ void rot(float& c, float& s, float stc, float sts) {
  float t1 = s * sts;
  float t2 = s * stc;
  float cn = fmaf(c, stc, -t1);
  s = fmaf(c, sts, t2);
  c = cn;
}

__device__ __forceinline__ void start_i_pow(int n, float& c, float& s) {
  switch (n & 3) {
    case 0: c = 1.f; s = 0.f; break;
    case 1: c = 0.f; s = 1.f; break;
    case 2: c = -1.f; s = 0.f; break;
    default: c = 0.f; s = -1.f; break;
  }
}

// K1: T[d][a][v] = sum_b yw[d,a,b] * e^{-2pi i v (b-40)/160}, v in 0..80
__global__ __launch_bounds__(256) void k_fft_x(const float* __restrict__ patch,
                                               const float* __restrict__ gw,
                                               float2* __restrict__ T) {
  int idx = blockIdx.x * 256 + threadIdx.x;   // ND*NP*NV = 414720
  int v = idx % NV;
  int a = (idx / NV) % NP;
  int d = idx / (NV * NP);
  float c, s;
  start_i_pow(v, c, s);
  float stc, sts;
  sincosf(-TWO_PI * (float)v / (float)NF, &sts, &stc);
  const float* prow = patch + (size_t)(d * NP + a) * NP;
  const float* grow = gw + a * NP;
  float accR = 0.f, accI = 0.f;
#pragma unroll 4
  for (int b = 0; b < NP; ++b) {
    float f = prow[b] * grow[b];
    accR = fmaf(f, c, accR);
    accI = fmaf(f, s, accI);
    rot(c, s, stc, sts);
  }
  T[idx] = make_float2(accR, accI);
}

// K2: Y[d][u][v] = sum_a T[d][a][v] * e^{-2pi i u (a-40)/160}
__global__ __launch_bounds__(256) void k_fft_y(const float2* __restrict__ T,
                                               float2* __restrict__ Y) {
  int idx = blockIdx.x * 256 + threadIdx.x;   // 64*40*81 = 207360
  int v = idx % NV;
  int ug = (idx / NV) % 40;
  int d = idx / (NV * 40);
  float c[4], s[4], aR[4], aI[4], stc[4], sts[4];
#pragma unroll
  for (int j = 0; j < 4; ++j) {
    int u = ug * 4 + j;
    start_i_pow(u, c[j], s[j]);
    sincosf(-TWO_PI * (float)u / (float)NF, &sts[j], &stc[j]);
    aR[j] = 0.f; aI[j] = 0.f;
  }
  const float2* Tb = T + (size_t)(d * NP) * NV + v;
#pragma unroll 4
  for (int a = 0; a < NP; ++a) {
    float2 t = Tb[(size_t)a * NV];
#pragma unroll
    for (int j = 0; j < 4; ++j) {
      aR[j] = fmaf(t.x, c[j], aR[j]);
      aR[j] = fmaf(-t.y, s[j], aR[j]);
      aI[j] = fmaf(t.x, s[j], aI[j]);
      aI[j] = fmaf(t.y, c[j], aI[j]);
      rot(c[j], s[j], stc[j], sts[j]);
    }
  }
#pragma unroll
  for (int j = 0; j < 4; ++j) {
    int u = ug * 4 + j;
    Y[((size_t)d * NF + u) * NV + v] = make_float2(aR[j], aI[j]);
  }
}

// K3: fused prep+cand. Block owns an exclusive 8-pixel stripe:
//  prep: thread (px = t>>4, dg = t&15) does 4 d's (sincos + Y load),
//        width-16 shfl moment reduce, yk quad-pack via LDS; dg==0 writes
//        param quads + prm slots.
//  cand: CPT=4 candidates/thread (all 512 in one 128-thread block),
//        one LDS record read feeds 4 Chebyshev chains, private accumulator.
__global__ __launch_bounds__(BT) void k_cand(const float2* __restrict__ Y,
                                             const float* __restrict__ delays,
                                             const float* __restrict__ kloss,
                                             const float* __restrict__ theta,
                                             const float* __restrict__ cand,
                                             float* __restrict__ partial,
                                             float* __restrict__ prm) {
  __shared__ float4 buf[STRIPE][RECQ];        // 2688 B record
  __shared__ float ykl[STRIPE][65];           // 2080 B (padded)
  int t = threadIdx.x;
  int p0 = blockIdx.x * STRIPE;               // 1632*8 = 13056 exactly

  // ---- prep phase ----
  {
    int px = t >> 4;                          // 0..7
    int dg = t & 15;                          // 0..15
    int p = p0 + px;
    bool valid = p < NPIXH;
    float k = 0.f, c2t = 0.f, s2t = 0.f, wgt = 0.f;
    int u = 0, v = 0;
    if (valid) {
      u = p / NV; v = p - u * NV;
      k = kloss[u * NF + v];
      float th = theta[((u + 80) % NF) * NF + ((v + 80) % NF)];
      c2t = cosf(2.f * th); s2t = sinf(2.f * th);
      if (v == 0 || v == 80) {
        if (u == 0 || u == 80) wgt = 1.f;
        else if (u < 80) wgt = 2.f;
        else wgt = 0.f;
      } else wgt = 2.f;
    }
    float mAr = 0.f, mAi = 0.f, mBr = 0.f, mBi = 0.f;
    float mP = 0.f, mQ = 0.f, mR = 0.f, mS = 0.f;
    float cd0t = 1.f, sd0t = 0.f, cd1t = 1.f, sd1t = 0.f;
#pragma unroll
    for (int j = 0; j < 4; ++j) {
      int d = dg * 4 + j;
      float sd, cd;
      sincosf(k * delays[d], &sd, &cd);
      float yx = 0.f, yy = 0.f;
      if (valid) {
        float2 y = Y[((size_t)d * NF + u) * NV + v];
        yx = y.x; yy = y.y;
      }
      mAr = fmaf(yx, cd, mAr);  mAi = fmaf(yy, cd, mAi);
      mBr = fmaf(yx, sd, mBr);  mBi = fmaf(yy, sd, mBi);
      mP = fmaf(cd, cd, mP);  mQ = fmaf(cd, sd, mQ);  mR = fmaf(sd, sd, mR);
      float yk = sqrtf(fmaf(yx, yx, yy * yy)) * k;
      ykl[px][d] = yk;
      mS = fmaf(yk, yk, mS);
      if (j == 0) { cd0t = cd; sd0t = sd; }
      if (j == 1) { cd1t = cd; sd1t = sd; }
    }
    // reduce moments over the 16 dg lanes (same wave, width-16 butterflies)
#pragma unroll
    for (int off = 8; off > 0; off >>= 1) {
      mAr += __shfl_xor(mAr, off);
      mAi += __shfl_xor(mAi, off);
      mBr += __shfl_xor(mBr, off);
      mBi += __shfl_xor(mBi, off);
      mP += __shfl_xor(mP, off);
      mQ += __shfl_xor(mQ, off);
      mR += __shfl_xor(mR, off);
      mS += __shfl_xor(mS, off);
    }
    if (dg == 0) {
      if (valid) {
        float tcd = 2.f * cosf(k * (delays[1] - delays[0]));
        buf[px][16] = make_float4(mAr, mAi, mBr, mBi);
        buf[px][17] = make_float4(mP, mQ, mR, mS);
        buf[px][18] = make_float4(c2t, s2t, k, wgt);
        buf[px][19] = make_float4(cd0t, sd0t, cd1t, sd1t);
        buf[px][20] = make_float4(tcd, 0.f, 0.f, 0.f);
        prm[IP_AR * NPIXP + p] = mAr;  prm[IP_AI * NPIXP + p] = mAi;
        prm[IP_BR * NPIXP + p] = mBr;  prm[IP_BI * NPIXP + p] = mBi;
        prm[IP_P * NPIXP + p] = mP;    prm[IP_Q * NPIXP + p] = mQ;
        prm[IP_R * NPIXP + p] = mR;    prm[IP_C2T * NPIXP + p] = c2t;
        prm[IP_S2T * NPIXP + p] = s2t; prm[IP_K * NPIXP + p] = k;
      } else {
        buf[px][16] = make_float4(0.f, 0.f, 0.f, 0.f);
        buf[px][17] = make_float4(1.f, 0.f, 1.f, 0.f);
        buf[px][18] = make_float4(0.f, 0.f, 0.f, 0.f);
        buf[px][19] = make_float4(1.f, 0.f, 1.f, 0.f);
        buf[px][20] = make_float4(2.f, 0.f, 0.f, 0.f);
      }
    }
    // yk quad-pack: thread (px2 = t>>4, jj = t&15) — same wave as writers
    int px2 = t >> 4, jj = t & 15;
    buf[px2][jj] = make_float4(ykl[px2][2 * jj], ykl[px2][63 - 2 * jj],
                               ykl[px2][2 * jj + 1], ykl[px2][62 - 2 * jj]);
  }
  __syncthreads();

  // ---- candidate phase (R15-identical) ----
  float dc[CPT], xx[CPT], yy[CPT], acc[CPT];
#pragma unroll
  for (int ci = 0; ci < CPT; ++ci) {
    int c = t + ci * BT;
    dc[ci] = cand[c * 3 + 0];
    xx[ci] = cand[c * 3 + 1];
    yy[ci] = cand[c * 3 + 2];
    acc[ci] = 0.f;
  }
#pragma unroll
  for (int i = 0; i < STRIPE; ++i) {
    const float4* r = &buf[i][0];
    float4 pA = r[16];                        // Ar,Ai,Br,Bi
    float4 pB = r[17];                        // Pm,Qm,Rm,S0
    float4 pC = r[18];                        // c2t,s2t,k,wgt
    float4 pD = r[19];                        // cd0,sd0,cd1,sd1
    float tcd = r[20].x;
    float4 y0 = r[0];
    float A0[CPT], A1[CPT], B0[CPT], B1[CPT], M[CPT], F0[CPT], F1[CPT];
#pragma unroll
    for (int ci = 0; ci < CPT; ++ci) {
      float w_ = fmaf(xx[ci], pC.x, fmaf(yy[ci], pC.y, dc[ci]));
      float sw, cw;
      __sincosf(pC.z * w_, &sw, &cw);
      float rr = fmaf(cw, pA.x, sw * pA.z);
      float ri = fmaf(cw, pA.y, sw * pA.w);
      float lhs = fmaf(cw * cw, pB.x, fmaf(2.f * cw * sw, pB.y, sw * sw * pB.z));
      float rabs = __builtin_amdgcn_sqrtf(fmaf(rr, rr, ri * ri));
      float rl = __builtin_amdgcn_rcpf(lhs);
      float e = fmaf(-lhs, rl, 1.f);
      rl = fmaf(rl, e, rl);                   // refined 1/lhs
      float kX = pC.z * rabs * rl;
      F0[ci] = fmaf(kX * kX, lhs, pB.w);      // contrib = F0 + F1*M
      F1[ci] = -2.f * kX;
      float t0 = pD.x * cw, u0 = pD.y * sw;
      float t1 = pD.z * cw, u1 = pD.w * sw;
      A0[ci] = t0 + u0;  B0[ci] = t0 - u0;    // cos(k d0 -/+ kw)
      A1[ci] = t1 + u1;  B1[ci] = t1 - u1;    // cos(k d1 -/+ kw)
      float m = y0.x * fabsf(A0[ci]);
      m = fmaf(y0.y, fabsf(B0[ci]), m);
      m = fmaf(y0.z, fabsf(A1[ci]), m);
      m = fmaf(y0.w, fabsf(B1[ci]), m);
      M[ci] = m;
    }
    float4 ykn = r[1];
#pragma unroll
    for (int jj = 1; jj < 16; ++jj) {
      float4 yk = ykn;
      if (jj < 15) ykn = r[jj + 1];           // 1-ahead prefetch
#pragma unroll
      for (int ci = 0; ci < CPT; ++ci) {
        float An = fmaf(tcd, A1[ci], -A0[ci]);
        float Bn = fmaf(tcd, B1[ci], -B0[ci]);
        float m = fmaf(yk.x, fabsf(An), M[ci]);
        m = fmaf(yk.y, fabsf(Bn), m);
        float An2 = fmaf(tcd, An, -A1[ci]);
        float Bn2 = fmaf(tcd, Bn, -B1[ci]);
        m = fmaf(yk.z, fabsf(An2), m);
        m = fmaf(yk.w, fabsf(Bn2), m);
        M[ci] = m;
        A0[ci] = An; A1[ci] = An2;
        B0[ci] = Bn; B1[ci] = Bn2;
      }
    }
#pragma unroll
    for (int ci = 0; ci < CPT; ++ci)
      acc[ci] = fmaf(fmaf(F1[ci], M[ci], F0[ci]), pC.w, acc[ci]);
  }
#pragma unroll
  for (int ci = 0; ci < CPT; ++ci)
    partial[(size_t)blockIdx.x * NC + t + ci * BT] = acc[ci];
}

// K4: loss[c] = sum over stripes — one block per candidate, parallel loads,
// deterministic LDS tree reduction.
__global__ __launch_bounds__(256) void k_sum(const float* __restrict__ partial,
                                             float* __restrict__ loss) {
  __shared__ float red[256];
  int c = blockIdx.x;                         // 512 blocks
  float s = 0.f;
  for (int j = threadIdx.x; j < NSTR; j += 256)
    s += partial[(size_t)j * NC + c];
  red[threadIdx.x] = s;
  __syncthreads();
  for (int off = 128; off > 0; off >>= 1) {
    if (threadIdx.x < off) red[threadIdx.x] += red[threadIdx.x + off];
    __syncthreads();
  }
  if (threadIdx.x == 0) loss[c] = red[0];
}

// K5: fused redundant argmin (per block) + ifft_u row DFT (blocks 0..159)
__global__ __launch_bounds__(256) void k_amin_ifftu(const float* __restrict__ loss,
                                                    const float* __restrict__ prm,
                                                    const float* __restrict__ cand,
                                                    float* __restrict__ out,
                                                    float2* __restrict__ G) {
  __shared__ float sl[256];
  __shared__ int si[256];
  __shared__ float xr[NF], xi[NF];
  int c1 = threadIdx.x, c2 = threadIdx.x + 256;
  float s1 = loss[c1], s2 = loss[c2];
  float l; int i;
  if (s2 < s1) { l = s2; i = c2; } else { l = s1; i = c1; }
  sl[threadIdx.x] = l; si[threadIdx.x] = i;
  __syncthreads();
  for (int off = 128; off > 0; off >>= 1) {
    if (threadIdx.x < off) {
      float l2 = sl[threadIdx.x + off]; int i2 = si[threadIdx.x + off];
      if (l2 < sl[threadIdx.x] || (l2 == sl[threadIdx.x] && i2 < si[threadIdx.x])) {
        sl[threadIdx.x] = l2; si[threadIdx.x] = i2;
      }
    }
    __syncthreads();
  }
  int bi = si[0];
  if (blockIdx.x == 0 && threadIdx.x == 0) {
    out[6400] = cand[bi * 3 + 0];
    out[6401] = cand[bi * 3 + 1];
    out[6402] = cand[bi * 3 + 2];
    out[6403] = sl[0] * (1.f / 1638400.f);
  }
  int u = blockIdx.x;
  float dc = cand[bi * 3 + 0], xx = cand[bi * 3 + 1], yy = cand[bi * 3 + 2];
  int v = threadIdx.x;
  if (v < NF) {
    float sign = 1.f;
    int ph;
    if (v <= 80) {
      ph = u * NV + v;
    } else {
      int u2 = (NF - u) % NF;
      ph = u2 * NV + (NF - v);
      sign = -1.f;
    }
    float Ar = prm[IP_AR * NPIXP + ph], Ai = prm[IP_AI * NPIXP + ph];
    float Br = prm[IP_BR * NPIXP + ph], Bi = prm[IP_BI * NPIXP + ph];
    float Pm = prm[IP_P * NPIXP + ph], Qm = prm[IP_Q * NPIXP + ph], Rm = prm[IP_R * NPIXP + ph];
    float c2t = prm[IP_C2T * NPIXP + ph], s2t = prm[IP_S2T * NPIXP + ph];
    float k = prm[IP_K * NPIXP + ph];
    float w_ = fmaf(xx, c2t, fmaf(yy, s2t, dc));
    float sw, cw;
    sincosf(k * w_, &sw, &cw);
    float rr = fmaf(cw, Ar, sw * Br);
    float ri = fmaf(cw, Ai, sw * Bi);
    float lhs = fmaf(cw * cw, Pm, fmaf(2.f * cw * sw, Qm, sw * sw * Rm));
    xr[v] = rr / lhs;
    xi[v] = sign * ri / lhs;
  }
  __syncthreads();
  int b = threadIdx.x;
  if (b < NP) {
    int xb = (b + 120) % NF;
    float stc, sts;
    sincosf(TWO_PI * (float)xb / (float)NF, &sts, &stc);
    float c = 1.f, s = 0.f, accR = 0.f, accI = 0.f;
#pragma unroll 4
    for (int vv = 0; vv < NF; ++vv) {
      float xrv = xr[vv], xiv = xi[vv];
      accR = fmaf(xrv, c, accR); accR = fmaf(-xiv, s, accR);
      accI = fmaf(xrv, s, accI); accI = fmaf(xiv, c, accI);
      rot(c, s, stc, sts);
    }
    G[(size_t)u * NP + b] = make_float2(accR, accI);
  }
}

// K6: ifft_y u-sliced 4-way: block = 4 slices x 64 outputs, grid = 100.
__global__ __launch_bounds__(256) void k_ifft_y(const float2* __restrict__ G,
                                                float* __restrict__ out) {
  __shared__ float red[4][65];
  int t = threadIdx.x;
  int o = t & 63;
  int slc = t >> 6;                           // 0..3, u in [40*slc, 40*slc+40)
  int idx = blockIdx.x * 64 + o;              // 6400 outputs
  int b = idx % NP;
  int a = idx / NP;
  int ya = (a + 120) % NF;
  float stc, sts;
  sincosf(TWO_PI * (float)ya / (float)NF, &sts, &stc);
  float c, s;
  start_i_pow(ya * slc, c, s);                // e^{2pi i ya (40 slc)/160} = i^(ya slc)
  float accR = 0.f;
  const float2* Gb = G + (size_t)(slc * 40) * NP + b;
#pragma unroll 4
  for (int j = 0; j < 40; ++j) {
    float2 g = Gb[(size_t)j * NP];
    accR = fmaf(g.x, c, accR);
    accR = fmaf(-g.y, s, accR);
    rot(c, s, stc, sts);
  }
  red[slc][o] = accR;
  __syncthreads();
  if (t < 64) {
    float s4 = ((red[0][t] + red[1][t]) + (red[2][t] + red[3][t]));
    out[blockIdx.x * 64 + t] = s4 * (1.f / 25600.f);
  }
}

extern "C" void kernel_launch(void* const* d_in, const int* in_sizes, int n_in,
                              void* d_out, int out_size, void* d_ws, size_t ws_size,
                              hipStream_t stream) {
  (void)in_sizes; (void)n_in; (void)out_size; (void)ws_size;
  const float* patch  = (const float*)d_in[0];
  const float* gw     = (const float*)d_in[1];
  const float* delays = (const float*)d_in[2];
  const float* theta  = (const float*)d_in[4];
  const float* kloss  = (const float*)d_in[5];
  const float* cand   = (const float*)d_in[6];
  float* out = (float*)d_out;

  char* ws = (char*)d_ws;
  size_t off = 0;
  float2* Y = (float2*)(ws + off);      off += (size_t)ND * NF * NV * 8;     // 6,635,520
  float2* T = (float2*)(ws + off);      off += (size_t)ND * NP * NV * 8;     // 3,317,760
  float* prm = (float*)(ws + off);      off += (size_t)NPRM * NPIXP * 4;     //   522,240
  float* partial = (float*)(ws + off);  off += (size_t)NSTR * NC * 4;        // 3,342,336
  float* loss = (float*)(ws + off);     off += (size_t)NC * 4;               //     2,048
  float2* G = (float2*)(ws + off);      off += (size_t)NF * NP * 8;          //   102,400

  hipLaunchKernelGGL(k_fft_x, dim3((ND * NP * NV) / 256), dim3(256), 0, stream, patch, gw, T);
  hipLaunchKernelGGL(k_fft_y, dim3((ND * 40 * NV) / 256), dim3(256), 0, stream, T, Y);
  hipLaunchKernelGGL(k_cand, dim3(NSTR), dim3(BT), 0, stream, Y, delays, kloss, theta, cand, partial, prm);
  hipLaunchKernelGGL(k_sum, dim3(NC), dim3(256), 0, stream, partial, loss);
  hipLaunchKernelGGL(k_amin_ifftu, dim3(NF), dim3(256), 0, stream, loss, prm, cand, out, G);
  hipLaunchKernelGGL(k_ifft_y, dim3(100), dim3(256), 0, stream, G, out);
}